// Round 7
// baseline (4012.881 us; speedup 1.0000x reference)
//
#include <hip/hip_runtime.h>

#define NTOK   32768
#define DDIM   512
#define KCODES 8192
#define DK     (DDIM * KCODES)      // 4194304
#define DECAYF 0.8f
#define EPSF   1e-5f

using short8 = __attribute__((ext_vector_type(8))) short;
using f32x4  = __attribute__((ext_vector_type(4))) float;

// ---------------- ws layout (float offsets) ----------------
// esumT [K][D] (zeroed in prep, atomic-accum in G's fused gather)
// onehot [K]   (zeroed in prep, atomic in G)
// e_norm [K]   (plain-stored complete codebook norms)
// scal [64]    (0=loss accum; 2+b = cluster_size partial sums)
// cnt [256]    (per-token-row completion counters, zeroed in prep)
// partials NTOK u64 (0xFF-init, atomicMin in G)
// ehi/elo [K][D] bf16 hi/lo codebook
#define WS_ESUMT  0
#define WS_ONEHOT DK
#define WS_ENORM  (DK + 8192)
#define WS_SCAL   (DK + 16384)
#define WS_CNT    (WS_SCAL + 64)
#define WS_PART   (WS_CNT + 256)
#define WS_EHI    (WS_PART + 2 * NTOK)
#define WS_ELO    (WS_EHI + DK / 2)

__device__ __forceinline__ unsigned short bf16rne(float f) {
  unsigned u = __float_as_uint(f);
  unsigned r = u + 0x7FFFu + ((u >> 16) & 1u);
  return (unsigned short)(r >> 16);
}

__device__ __forceinline__ float bf2f(unsigned short h) {
  return __uint_as_float((unsigned)h << 16);
}

__device__ __forceinline__ void gload_lds16(const unsigned short* g, unsigned short* l) {
  __builtin_amdgcn_global_load_lds(
      (const __attribute__((address_space(1))) unsigned int*)g,
      (__attribute__((address_space(3))) unsigned int*)l, 16, 0, 0);
}

// ============ K1: fused prep (R4 + cnt zeroing) ============
__global__ __launch_bounds__(256) void prep_kernel(
    const float* __restrict__ x, const float* __restrict__ embed,
    const float* __restrict__ cluster_size,
    unsigned short* __restrict__ xhi, unsigned short* __restrict__ xlo,
    unsigned short* __restrict__ ehi, unsigned short* __restrict__ elo,
    float* __restrict__ e_norm, float* __restrict__ esumT,
    float* __restrict__ onehot, float* __restrict__ scal,
    unsigned* __restrict__ cnt, unsigned long long* __restrict__ partials) {
  __shared__ float tile[32][33];
  __shared__ float part[8][32];
  __shared__ float w[4];
  const int bid = blockIdx.x;
  const int tid = threadIdx.x;

  if (bid < 8192) {
    // ---- split x into bf16 hi/lo ----
    const size_t i = ((size_t)bid * 256 + tid) * 8;
    const float4 v0 = *(const float4*)&x[i];
    const float4 v1 = *(const float4*)&x[i + 4];
    const float v[8] = {v0.x, v0.y, v0.z, v0.w, v1.x, v1.y, v1.z, v1.w};
    unsigned short h[8], l[8];
#pragma unroll
    for (int j = 0; j < 8; ++j) {
      h[j] = bf16rne(v[j]);
      l[j] = bf16rne(v[j] - bf2f(h[j]));
    }
    uint4 H, L;
    H.x = h[0] | ((unsigned)h[1] << 16); H.y = h[2] | ((unsigned)h[3] << 16);
    H.z = h[4] | ((unsigned)h[5] << 16); H.w = h[6] | ((unsigned)h[7] << 16);
    L.x = l[0] | ((unsigned)l[1] << 16); L.y = l[2] | ((unsigned)l[3] << 16);
    L.z = l[4] | ((unsigned)l[5] << 16); L.w = l[6] | ((unsigned)l[7] << 16);
    *(uint4*)&xhi[i] = H;
    *(uint4*)&xlo[i] = L;
  } else if (bid < 8192 + 256) {
    // ---- transpose embed: 32 codes/block, full D, complete norm ----
    const int k0 = (bid - 8192) * 32;
    const int tx = tid & 31;
    const int ty = tid >> 5;
    float sq = 0.f;
#pragma unroll 1
    for (int d0 = 0; d0 < DDIM; d0 += 32) {
      __syncthreads();
#pragma unroll
      for (int j = 0; j < 4; ++j) {
        const int dl = ty + j * 8;
        const float v = embed[(size_t)(d0 + dl) * KCODES + k0 + tx];
        tile[dl][tx] = v;
        sq += v * v;
      }
      __syncthreads();
#pragma unroll
      for (int j = 0; j < 4; ++j) {
        const int kl = ty + j * 8;
        const size_t idx = (size_t)(k0 + kl) * DDIM + d0 + tx;
        const float v = tile[tx][kl];
        const unsigned short h = bf16rne(v);
        ehi[idx] = h;
        elo[idx] = bf16rne(v - bf2f(h));
      }
    }
    part[ty][tx] = sq;
    __syncthreads();
    if (ty == 0) {
      float s = 0.f;
#pragma unroll
      for (int j = 0; j < 8; ++j) s += part[j][tx];
      e_norm[k0 + tx] = s;
    }
  } else if (bid < 8192 + 256 + 2048) {
    // ---- zero esumT ----
    const int zb = bid - (8192 + 256);
    const size_t off = (size_t)zb * 2048 + (size_t)tid * 8;
    const float4 z = {0.f, 0.f, 0.f, 0.f};
    *(float4*)&esumT[off] = z;
    *(float4*)&esumT[off + 4] = z;
  } else {
    // ---- misc init: 32 blocks ----
    const int b = bid - (8192 + 256 + 2048);    // 0..31
    onehot[b * 256 + tid] = 0.f;
    const size_t pbase = (size_t)b * 1024 + (size_t)tid * 4;
    const ulonglong2 ff = {~0ull, ~0ull};
    *(ulonglong2*)&partials[pbase] = ff;
    *(ulonglong2*)&partials[pbase + 2] = ff;
    if (b == 0) cnt[tid] = 0u;
    float s = cluster_size[b * 256 + tid];
#pragma unroll
    for (int off = 32; off > 0; off >>= 1) s += __shfl_down(s, off);
    if ((tid & 63) == 0) w[tid >> 6] = s;
    __syncthreads();
    if (tid == 0) {
      scal[2 + b] = w[0] + w[1] + w[2] + w[3];
      if (b == 0) { scal[0] = 0.f; scal[1] = 0.f; }
    }
  }
}

// ============ K2: proven 128x128 MFMA dist GEMM + argmin + last-arrival stats ============
__global__ __launch_bounds__(256) void argmin_mfma_kernel(
    const unsigned short* __restrict__ xhi, const unsigned short* __restrict__ xlo,
    const unsigned short* __restrict__ ehi, const unsigned short* __restrict__ elo,
    const float* __restrict__ e_norm, unsigned long long* __restrict__ partials,
    const float* __restrict__ x, float* __restrict__ indf_out,
    float* __restrict__ onehot, float* __restrict__ esumT,
    float* __restrict__ scal, unsigned* __restrict__ cnt) {
  __shared__ unsigned short Ahs[128 * 32];   // 8 KB each
  __shared__ unsigned short Als[128 * 32];
  __shared__ unsigned short Bhs[128 * 32];
  __shared__ unsigned short Bls[128 * 32];

  const int t    = threadIdx.x;
  const int wid  = t >> 6;
  const int lid  = t & 63;
  const int kblk = blockIdx.x;              // 0..63
  const int tokbase = blockIdx.y * 128;
  const int kbase   = kblk * 128;

  const int wrow = wid >> 1, wcol = wid & 1;    // 2x2 wave grid, 64x64 each
  const int m16  = lid & 15, kq = lid >> 4;

  const int srow = lid >> 2;                                  // 0..15
  const int gcol = ((lid & 3) ^ ((srow >> 1) & 3)) * 8;       // swizzled source
  const int fsw = (kq ^ ((m16 >> 1) & 3)) * 8;

  f32x4 acc[4][4];
#pragma unroll
  for (int i = 0; i < 4; ++i)
#pragma unroll
    for (int j = 0; j < 4; ++j) acc[i][j] = (f32x4)0.f;

  const unsigned short* Ahg = xhi + (size_t)tokbase * DDIM;
  const unsigned short* Alg = xlo + (size_t)tokbase * DDIM;
  const unsigned short* Bhg = ehi + (size_t)kbase * DDIM;
  const unsigned short* Blg = elo + (size_t)kbase * DDIM;

#pragma unroll 1
  for (int d0 = 0; d0 < DDIM; d0 += 32) {
    __syncthreads();
#pragma unroll
    for (int p = 0; p < 2; ++p) {
      const int chunk = wid + p * 4;                       // wave-uniform
      const size_t go = (size_t)(chunk * 16 + srow) * DDIM + d0 + gcol;
      gload_lds16(Ahg + go, &Ahs[chunk * 512]);
      gload_lds16(Alg + go, &Als[chunk * 512]);
      gload_lds16(Bhg + go, &Bhs[chunk * 512]);
      gload_lds16(Blg + go, &Bls[chunk * 512]);
    }
    __syncthreads();
    short8 bh[4], bl[4];
#pragma unroll
    for (int j = 0; j < 4; ++j) {
      const int r = (wcol * 64 + j * 16 + m16) * 32 + fsw;
      bh[j] = *(const short8*)&Bhs[r];
      bl[j] = *(const short8*)&Bls[r];
    }
#pragma unroll
    for (int i = 0; i < 4; ++i) {
      const int r = (wrow * 64 + i * 16 + m16) * 32 + fsw;
      const short8 ah = *(const short8*)&Ahs[r];
      const short8 al = *(const short8*)&Als[r];
#pragma unroll
      for (int j = 0; j < 4; ++j) {
        acc[i][j] = __builtin_amdgcn_mfma_f32_16x16x32_bf16(ah, bh[j], acc[i][j], 0, 0, 0);
        acc[i][j] = __builtin_amdgcn_mfma_f32_16x16x32_bf16(ah, bl[j], acc[i][j], 0, 0, 0);
        acc[i][j] = __builtin_amdgcn_mfma_f32_16x16x32_bf16(al, bh[j], acc[i][j], 0, 0, 0);
      }
    }
  }

  // ---- fused argmin epilogue: score = ||e_k||^2 - 2*dot ----
  float en[4];
#pragma unroll
  for (int j = 0; j < 4; ++j)
    en[j] = e_norm[kbase + wcol * 64 + j * 16 + m16];

  __syncthreads();
  unsigned long long* red = (unsigned long long*)Ahs;   // [128][2], 2 KB
#pragma unroll
  for (int i = 0; i < 4; ++i) {
#pragma unroll
    for (int r = 0; r < 4; ++r) {
      unsigned long long best = 0xFFFFFFFFFFFFFFFFull;
#pragma unroll
      for (int j = 0; j < 4; ++j) {
        const float s = en[j] - 2.0f * acc[i][j][r];
        unsigned u = __float_as_uint(s);
        u = (u & 0x80000000u) ? ~u : (u | 0x80000000u);  // orderable bits
        const unsigned k = (unsigned)(kbase + wcol * 64 + j * 16 + m16);
        const unsigned long long c = ((unsigned long long)u << 32) | k;
        best = (c < best) ? c : best;
      }
#pragma unroll
      for (int s = 1; s < 16; s <<= 1) {
        const unsigned long long c = __shfl_xor(best, s);
        best = (c < best) ? c : best;
      }
      if (m16 == 0)
        red[(wrow * 64 + i * 16 + kq * 4 + r) * 2 + wcol] = best;
    }
  }
  __syncthreads();
  if (t < 128) {
    const unsigned long long a0 = red[t * 2], a1 = red[t * 2 + 1];
    const unsigned long long m = (a0 < a1) ? a0 : a1;
    atomicMin(&partials[tokbase + t], m);
  }

  // ---- last-arrival fused stats gather for this token row ----
  __threadfence();          // make this block's atomicMins device-visible
  __syncthreads();
  int* s_last = (int*)Als;
  float* gred = (float*)(Als + 16);
  if (t == 0) {
    const unsigned v = atomicAdd(&cnt[blockIdx.y], 1u);
    *s_last = (v == 63u);   // 64th arriver: all partials for this row final
  }
  __syncthreads();
  if (*s_last) {
    __threadfence();
    float ls = 0.f;
#pragma unroll 1
    for (int i = 0; i < 32; ++i) {
      const int n = tokbase + i * 4 + wid;
      unsigned long long pv = 0ull;
      if (lid == 0) pv = atomicAdd(&partials[n], 0ull);   // coherent read
      int k = (int)(pv & 0xFFFFFFFFull);
      k = __shfl(k, 0);
      if (lid == 0) {
        indf_out[n] = (float)k;
        atomicAdd(&onehot[k], 1.0f);
      }
      const int d8 = lid * 8;
      const float4 xv0 = *(const float4*)&x[(size_t)n * DDIM + d8];
      const float4 xv1 = *(const float4*)&x[(size_t)n * DDIM + d8 + 4];
      const ushort4 h0 = *(const ushort4*)&ehi[(size_t)k * DDIM + d8];
      const ushort4 h1 = *(const ushort4*)&ehi[(size_t)k * DDIM + d8 + 4];
      const ushort4 l0 = *(const ushort4*)&elo[(size_t)k * DDIM + d8];
      const ushort4 l1 = *(const ushort4*)&elo[(size_t)k * DDIM + d8 + 4];
      const float xv[8] = {xv0.x, xv0.y, xv0.z, xv0.w, xv1.x, xv1.y, xv1.z, xv1.w};
      const float ev[8] = {
          bf2f(h0.x) + bf2f(l0.x), bf2f(h0.y) + bf2f(l0.y),
          bf2f(h0.z) + bf2f(l0.z), bf2f(h0.w) + bf2f(l0.w),
          bf2f(h1.x) + bf2f(l1.x), bf2f(h1.y) + bf2f(l1.y),
          bf2f(h1.z) + bf2f(l1.z), bf2f(h1.w) + bf2f(l1.w)};
#pragma unroll
      for (int j = 0; j < 8; ++j) {
        atomicAdd(&esumT[(size_t)k * DDIM + d8 + j], xv[j]);
        const float dx = ev[j] - xv[j];
        ls += dx * dx;
      }
    }
#pragma unroll
    for (int off = 32; off > 0; off >>= 1) ls += __shfl_down(ls, off);
    if (lid == 0) gred[wid] = ls;
    __syncthreads();
    if (t == 0) atomicAdd(&scal[0], gred[0] + gred[1] + gred[2] + gred[3]);
  }
}

// ============ K3: finalize (EMA outputs) + quantize gather-write ============
__global__ __launch_bounds__(256) void finalize_kernel(
    const float* __restrict__ embed_avg, const float* __restrict__ embed_sumT,
    const float* __restrict__ cluster_size, const float* __restrict__ onehot,
    const float* __restrict__ scal, const unsigned long long* __restrict__ partials,
    const unsigned short* __restrict__ ehi, const unsigned short* __restrict__ elo,
    float* __restrict__ out_embed, float* __restrict__ out_avg,
    float* __restrict__ out_ncs, float* __restrict__ out_loss,
    float* __restrict__ out_quant) {
  __shared__ float tile[32][33];
  __shared__ float sh_nsum;
  const int k0 = blockIdx.x * 32;
  const int d0 = blockIdx.y * 32;
  const int tx = threadIdx.x & 31;
  const int ty = threadIdx.x >> 5;

  // ---- quantize gather: 8 tokens per block (4096 blocks x 8 = NTOK) ----
  {
    const int nbase = (blockIdx.y * 256 + blockIdx.x) * 8;
    const int n = nbase + (threadIdx.x >> 5);           // 8 token groups of 32 thr
    const int k = (int)(partials[n] & 0xFFFFFFFFull);
    const int d16 = (threadIdx.x & 31) * 16;
#pragma unroll
    for (int c = 0; c < 4; ++c) {
      const ushort4 h4 = *(const ushort4*)&ehi[(size_t)k * DDIM + d16 + c * 4];
      const ushort4 l4 = *(const ushort4*)&elo[(size_t)k * DDIM + d16 + c * 4];
      float4 e;
      e.x = bf2f(h4.x) + bf2f(l4.x);
      e.y = bf2f(h4.y) + bf2f(l4.y);
      e.z = bf2f(h4.z) + bf2f(l4.z);
      e.w = bf2f(h4.w) + bf2f(l4.w);
      *(float4*)&out_quant[(size_t)n * DDIM + d16 + c * 4] = e;
    }
  }

  if (threadIdx.x == 0) {
    float s = 0.f;
#pragma unroll
    for (int b = 0; b < 32; ++b) s += scal[2 + b];
    sh_nsum = DECAYF * s + (1.0f - DECAYF) * (float)NTOK;
  }
#pragma unroll
  for (int j = 0; j < 4; ++j) {
    const int kl = ty + j * 8;
    tile[kl][tx] = embed_sumT[(size_t)(k0 + kl) * DDIM + d0 + tx];
  }
  __syncthreads();
  const float nsum = sh_nsum;
  const float ncs = DECAYF * cluster_size[k0 + tx] + (1.0f - DECAYF) * onehot[k0 + tx];
  const float csv = (ncs + EPSF) / (nsum + (float)KCODES * EPSF) * nsum;
#pragma unroll
  for (int j = 0; j < 4; ++j) {
    const int dl = ty + j * 8;
    const size_t idx = (size_t)(d0 + dl) * KCODES + k0 + tx;
    const float nea = DECAYF * embed_avg[idx] + (1.0f - DECAYF) * tile[tx][dl];
    out_avg[idx] = nea;
    out_embed[idx] = nea / csv;
  }
  if (blockIdx.y == 0 && ty == 0)
    out_ncs[k0 + tx] = ncs;
  if (blockIdx.x == 0 && blockIdx.y == 0 && threadIdx.x == 0)
    out_loss[0] = scal[0] * (1.0f / ((float)NTOK * (float)DDIM));
}

extern "C" void kernel_launch(void* const* d_in, const int* in_sizes, int n_in,
                              void* d_out, int out_size, void* d_ws, size_t ws_size,
                              hipStream_t stream) {
  (void)in_sizes; (void)n_in; (void)out_size; (void)ws_size;
  const float* x            = (const float*)d_in[0];   // [NTOK, 512]
  const float* embed        = (const float*)d_in[1];   // [D, K]
  const float* cluster_size = (const float*)d_in[2];   // [K]
  const float* embed_avg    = (const float*)d_in[3];   // [D, K]

  float* out = (float*)d_out;
  float* out_quant = out;                               // 16777216
  float* out_indf  = out + 16777216;                    // 32768
  float* out_loss  = out + 16777216 + 32768;            // 1
  float* out_embed = out + 16777216 + 32768 + 1;        // 4194304 (odd offset)
  float* out_ncs   = out_embed + DK;                    // 8192
  float* out_avg   = out_ncs + KCODES;                  // 4194304

  float* ws = (float*)d_ws;
  float* esumT  = ws + WS_ESUMT;
  float* onehot = ws + WS_ONEHOT;
  float* e_norm = ws + WS_ENORM;
  float* scal   = ws + WS_SCAL;
  unsigned* cnt = (unsigned*)(ws + WS_CNT);
  unsigned long long* partials = (unsigned long long*)(ws + WS_PART);
  unsigned short* ehi = (unsigned short*)(ws + WS_EHI);
  unsigned short* elo = (unsigned short*)(ws + WS_ELO);

  // x hi/lo scratch lives in the out_quant region; overwritten only by
  // finalize_kernel's quant gather (strictly after argmin_mfma completes).
  unsigned short* xhi = (unsigned short*)d_out;
  unsigned short* xlo = xhi + (size_t)NTOK * DDIM;

  // 3 dispatches total.
  prep_kernel<<<8192 + 256 + 2048 + 32, 256, 0, stream>>>(
      x, embed, cluster_size, xhi, xlo, ehi, elo, e_norm, esumT, onehot, scal,
      cnt, partials);

  argmin_mfma_kernel<<<dim3(64, 256), 256, 0, stream>>>(
      xhi, xlo, ehi, elo, e_norm, partials,
      x, out_indf, onehot, esumT, scal, cnt);

  finalize_kernel<<<dim3(KCODES / 32, DDIM / 32), 256, 0, stream>>>(
      embed_avg, esumT, cluster_size, onehot, scal, partials, ehi, elo,
      out_embed, out_avg, out_ncs, out_loss, out_quant);
}